// Round 12
// baseline (632.742 us; speedup 1.0000x reference)
//
#include <hip/hip_runtime.h>

#define NG   4096
#define P    24
#define EPG  192
#define DIN  32
#define H    128
#define NOUT 3
#define HSS  136   // f16 row stride for [24][H] tiles (272B rows, 16B-aligned)
#define XSS  40    // x-stage row stride (80B, 16B-aligned)

// per-wave LDS region layout (bytes)
#define O_HB    0        // hb  [24][HSS] f16, 6528 (also x-stage [32][XSS] at start)
#define O_XLB   6528     // xlb [24][HSS] f16, 6528
#define O_XRB   13056    // xrb [24][HSS] f16, 6528
#define O_ALP   19584    // alpha/ex f32[216] 864  (later: head scratch z/h2)
#define O_DSUM  20448    // f32|int [32] 128       (CSR counts / exp-denoms)
#define O_ELIST 20576    // u16[216] 432  ((s<<8)|eid)
#define O_EOFF  21008    // u16[25] pad 64
#define O_ATH   21072    // u32[64] packed f16 att pairs, 256
#define LDS_SZ  21376    // -> 7 blocks/CU (163840/21376)

typedef _Float16 f16x8 __attribute__((ext_vector_type(8)));
typedef _Float16 h2    __attribute__((ext_vector_type(2)));
typedef float    f32x4 __attribute__((ext_vector_type(4)));

__device__ __forceinline__ unsigned short f2h(float v) {
    _Float16 h = (_Float16)v; unsigned short u; __builtin_memcpy(&u, &h, 2); return u;
}
__device__ __forceinline__ float h2f(unsigned short u) {
    _Float16 h; __builtin_memcpy(&h, &u, 2); return (float)h;
}
__device__ __forceinline__ unsigned pkadd(unsigned a, unsigned b) {
    h2 x, y; __builtin_memcpy(&x, &a, 4); __builtin_memcpy(&y, &b, 4);
    h2 z = x + y; unsigned r; __builtin_memcpy(&r, &z, 4); return r;
}
// packed leaky-relu(0.2): max(x, 0.2x) elementwise on 2 f16
__device__ __forceinline__ unsigned lrpk(unsigned u) {
    h2 x; __builtin_memcpy(&x, &u, 4);
    h2 y = x * (h2){(_Float16)0.2f, (_Float16)0.2f};
    h2 m; m[0] = x[0] > y[0] ? x[0] : y[0]; m[1] = x[1] > y[1] ? x[1] : y[1];
    unsigned r; __builtin_memcpy(&r, &m, 4); return r;
}
__device__ __forceinline__ float lrelu(float v, float s) { return v > 0.f ? v : v * s; }

// paired b32 LDS store via DPP lane^1 exchange (pair-uniform exec required)
#define STPAIR(BASE, ROW, COL, VAL)                                           \
    do {                                                                      \
        unsigned o_ = (unsigned)__builtin_amdgcn_mov_dpp(                     \
            (int)(unsigned)(VAL), 0xB1, 0xF, 0xF, true);                      \
        if (!(lane & 1))                                                      \
            *reinterpret_cast<unsigned*>(&(BASE)[(ROW) * HSS + (COL)]) =      \
                (unsigned)(VAL) | (o_ << 16);                                 \
    } while (0)

// ---- prepass: convert/transpose weights to f16 in d_ws (unchanged) ----
__global__ void cvtw(const float* __restrict__ W0, const float* __restrict__ W1,
                     const float* __restrict__ Wl, const float* __restrict__ Wr,
                     const float* __restrict__ att, const float* __restrict__ bl,
                     const float* __restrict__ br, unsigned short* __restrict__ ws) {
    int i = blockIdx.x * 256 + threadIdx.x;
    if (i < 217088) {
        float v;
        if (i < 4096)        { int n = i >> 5, k = i & 31;  v = W0[k * 128 + n]; }
        else if (i < 20480)  { int j = i - 4096;  int n = j >> 7, k = j & 127; v = W1[k * 128 + n]; }
        else if (i < 118784) { int j = i - 20480; int c = j >> 14, r = j & 16383;
                               int n = r >> 7, k = r & 127; v = Wl[c * 16384 + k * 128 + n]; }
        else                 { int j = i - 118784; int c = j >> 14, r = j & 16383;
                               int n = r >> 7, k = r & 127; v = Wr[c * 16384 + k * 128 + n]; }
        ws[i] = f2h(v);
    }
}

__global__ __launch_bounds__(64, 2) void gat_all(
    const float* __restrict__ x,
    const int*   __restrict__ src,
    const int*   __restrict__ dst,
    const float* __restrict__ extra,
    const float* __restrict__ b0,  const float* __restrict__ b1,
    const float* __restrict__ bl,  const float* __restrict__ br,
    const float* __restrict__ att, const float* __restrict__ cbias,
    const float* __restrict__ Wf0, const float* __restrict__ bf0,
    const float* __restrict__ Wf1, const float* __restrict__ bf1,
    const float* __restrict__ Wf2, const float* __restrict__ bf2,
    const unsigned short* __restrict__ wsb,
    float* __restrict__ out)
{
    // ONE WAVE = ONE GRAPH. No __syncthreads anywhere: all LDS dependencies
    // are same-wave (DS ops execute in issue order within a wave).
    // A-frag reads of pad rows 24-31 over-read into the adjacent in-region
    // array (garbage, possibly NaN) — feeding ONLY suppressed stores; MFMA
    // D-row m depends only on A-row m, so real rows stay clean (R6/R7 lesson).
    __shared__ __align__(16) unsigned char L[LDS_SZ];
    unsigned short* hb    = (unsigned short*)(L + O_HB);
    unsigned short* xlb   = (unsigned short*)(L + O_XLB);
    unsigned short* xrb   = (unsigned short*)(L + O_XRB);
    float*          alp   = (float*)(L + O_ALP);
    float*          dsF   = (float*)(L + O_DSUM);
    int*            dsI   = (int*)(L + O_DSUM);
    unsigned short* elist = (unsigned short*)(L + O_ELIST);
    unsigned short* eoff  = (unsigned short*)(L + O_EOFF);
    unsigned*       ath   = (unsigned*)(L + O_ATH);

    const int g    = blockIdx.x;
    const int lane = threadIdx.x;          // 0..63 (one wave)
    const int m16  = lane & 15;
    const int kc   = lane >> 4;
    const long long gn = (long long)g * P;

    const unsigned short* W0T = wsb;
    const unsigned short* W1T = wsb + 4096;
    const unsigned short* WLT = wsb + 20480;
    const unsigned short* WRT = wsb + 118784;

    // ---------- prologue: own 3-4 edges, build CSR, stage x ----------
    int es[4], ed[4];
    #pragma unroll
    for (int q = 0; q < 3; ++q) {
        es[q] = src[(long long)g * EPG + lane + 64 * q] - (int)gn;
        ed[q] = dst[(long long)g * EPG + lane + 64 * q] - (int)gn;
    }
    es[3] = ed[3] = lane;                  // self-loop (valid for lane<24)
    const int ne = (lane < P) ? 4 : 3;

    // stage x (f16) into hb region as XS[32][XSS], rows 24-31 zeroed
    {
        unsigned short* XS = hb;
        #pragma unroll
        for (int i = 0; i < 12; ++i) {
            int idx = lane + i * 64;       // 0..767
            XS[(idx >> 5) * XSS + (idx & 31)] = f2h(x[gn * DIN + idx]);
        }
        #pragma unroll
        for (int i = 0; i < 5; ++i) XS[960 + lane + i * 64] = 0;  // rows 24-31
    }

    // CSR build (all same-wave, in-order LDS)
    if (lane < 32) dsI[lane] = 0;
    #pragma unroll
    for (int q = 0; q < 4; ++q) if (q < ne) atomicAdd(&dsI[ed[q]], 1);
    {
        int v = (lane < P) ? dsI[lane] : 0;
        #pragma unroll
        for (int dlt = 1; dlt <= 16; dlt <<= 1) {
            int u = __shfl_up(v, dlt);
            if (lane >= dlt) v += u;
        }
        if (lane < P) eoff[lane + 1] = (unsigned short)v;
        if (lane == 0) eoff[0] = 0;
    }
    if (lane < 32) dsI[lane] = 0;
    #pragma unroll
    for (int q = 0; q < 4; ++q) if (q < ne) {
        int pos = atomicAdd(&dsI[ed[q]], 1);
        int eid = (q < 3) ? (lane + 64 * q) : (192 + lane);
        elist[eoff[ed[q]] + pos] = (unsigned short)((es[q] << 8) | eid);
    }

    // ---------- init MLP layer 0: xlb = LR(x @ W0 + b0)  (K=32) ----------
    {
        unsigned short* XS = hb;
        f16x8 a0 = *reinterpret_cast<const f16x8*>(&XS[(m16)      * XSS + kc * 8]);
        f16x8 a1 = *reinterpret_cast<const f16x8*>(&XS[(16 + m16) * XSS + kc * 8]);
        #pragma unroll
        for (int nt = 0; nt < 8; ++nt) {
            f32x4 c0 = {}, c1 = {};
            f16x8 b = *reinterpret_cast<const f16x8*>(&W0T[(nt * 16 + m16) * 32 + kc * 8]);
            c0 = __builtin_amdgcn_mfma_f32_16x16x32_f16(a0, b, c0, 0, 0, 0);
            c1 = __builtin_amdgcn_mfma_f32_16x16x32_f16(a1, b, c1, 0, 0, 0);
            int col = nt * 16 + m16;
            float bv = b0[col];
            #pragma unroll
            for (int r = 0; r < 4; ++r) {
                unsigned short ub = f2h(lrelu(c0[r] + bv, 0.01f));
                STPAIR(xlb, kc * 4 + r, col, ub);
            }
            if (kc < 2) {
                #pragma unroll
                for (int r = 0; r < 4; ++r) {
                    unsigned short ub = f2h(lrelu(c1[r] + bv, 0.01f));
                    STPAIR(xlb, 16 + kc * 4 + r, col, ub);
                }
            }
        }
    }

    // ---------- init MLP layer 1: hb = LR(xlb @ W1 + b1)  (K=128) ----------
    {
        f16x8 a[2][4];
        #pragma unroll
        for (int mt = 0; mt < 2; ++mt)
        #pragma unroll
        for (int kt = 0; kt < 4; ++kt)
            a[mt][kt] = *reinterpret_cast<const f16x8*>(&xlb[(mt * 16 + m16) * HSS + kt * 32 + kc * 8]);
        #pragma unroll
        for (int nt = 0; nt < 8; ++nt) {
            f32x4 c0 = {}, c1 = {};
            #pragma unroll
            for (int kt = 0; kt < 4; ++kt) {
                f16x8 b = *reinterpret_cast<const f16x8*>(&W1T[(nt * 16 + m16) * 128 + kt * 32 + kc * 8]);
                c0 = __builtin_amdgcn_mfma_f32_16x16x32_f16(a[0][kt], b, c0, 0, 0, 0);
                c1 = __builtin_amdgcn_mfma_f32_16x16x32_f16(a[1][kt], b, c1, 0, 0, 0);
            }
            int col = nt * 16 + m16;
            float bv = b1[col];
            #pragma unroll
            for (int r = 0; r < 4; ++r) {
                unsigned short ub = f2h(lrelu(c0[r] + bv, 0.01f));
                STPAIR(hb, kc * 4 + r, col, ub);
            }
            if (kc < 2) {
                #pragma unroll
                for (int r = 0; r < 4; ++r) {
                    unsigned short ub = f2h(lrelu(c1[r] + bv, 0.01f));
                    STPAIR(hb, 16 + kc * 4 + r, col, ub);
                }
            }
        }
    }

    // ---------- 6 GATv2 convs, zero barriers ----------
    for (int c = 0; c < 6; ++c) {
        // xl = hb@Wl + bl ; xr = hb@Wr + br   (sequential, whole wave each)
        f16x8 a[2][4];
        #pragma unroll
        for (int mt = 0; mt < 2; ++mt)
        #pragma unroll
        for (int kt = 0; kt < 4; ++kt)
            a[mt][kt] = *reinterpret_cast<const f16x8*>(&hb[(mt * 16 + m16) * HSS + kt * 32 + kc * 8]);
        #pragma unroll
        for (int mm = 0; mm < 2; ++mm) {
            const unsigned short* WT = (mm ? WRT : WLT) + c * 16384;
            const float* bias = (mm ? br : bl) + c * H;
            unsigned short* XO = mm ? xrb : xlb;
            #pragma unroll
            for (int nt = 0; nt < 8; ++nt) {
                f32x4 c0 = {}, c1 = {};
                #pragma unroll
                for (int kt = 0; kt < 4; ++kt) {
                    f16x8 b = *reinterpret_cast<const f16x8*>(&WT[(nt * 16 + m16) * 128 + kt * 32 + kc * 8]);
                    c0 = __builtin_amdgcn_mfma_f32_16x16x32_f16(a[0][kt], b, c0, 0, 0, 0);
                    c1 = __builtin_amdgcn_mfma_f32_16x16x32_f16(a[1][kt], b, c1, 0, 0, 0);
                }
                int col = nt * 16 + m16;
                float bv = bias[col];
                #pragma unroll
                for (int r = 0; r < 4; ++r) {
                    unsigned short ub = f2h(c0[r] + bv);
                    STPAIR(XO, kc * 4 + r, col, ub);
                }
                if (kc < 2) {
                    #pragma unroll
                    for (int r = 0; r < 4; ++r) {
                        unsigned short ub = f2h(c1[r] + bv);
                        STPAIR(XO, 16 + kc * 4 + r, col, ub);
                    }
                }
            }
        }

        // edge phase: logits -> ex -> alp[eid], dsum via LDS atomics
        if (lane < 32) dsF[lane] = 0.f;
        ath[lane] = (unsigned)f2h(att[c * H + 2 * lane]) |
                    ((unsigned)f2h(att[c * H + 2 * lane + 1]) << 16);
        #pragma unroll
        for (int q = 0; q < 4; ++q) if (q < ne) {
            const int s = es[q], d = ed[q];
            const uint4* xa = reinterpret_cast<const uint4*>(&xlb[s * HSS]);
            const uint4* xb = reinterpret_cast<const uint4*>(&xrb[d * HSS]);
            const uint4* ap = reinterpret_cast<const uint4*>(ath);
            float t0 = 0.f, t1 = 0.f, t2 = 0.f, t3 = 0.f;
            #pragma unroll 4
            for (int cc = 0; cc < 16; ++cc) {
                uint4 wa = xa[cc], wb = xb[cc], pp = ap[cc];
                unsigned u0 = lrpk(pkadd(wa.x, wb.x));
                unsigned u1 = lrpk(pkadd(wa.y, wb.y));
                unsigned u2 = lrpk(pkadd(wa.z, wb.z));
                unsigned u3 = lrpk(pkadd(wa.w, wb.w));
                asm volatile("v_dot2_f32_f16 %0, %1, %2, %0" : "+v"(t0) : "v"(u0), "v"(pp.x));
                asm volatile("v_dot2_f32_f16 %0, %1, %2, %0" : "+v"(t1) : "v"(u1), "v"(pp.y));
                asm volatile("v_dot2_f32_f16 %0, %1, %2, %0" : "+v"(t2) : "v"(u2), "v"(pp.z));
                asm volatile("v_dot2_f32_f16 %0, %1, %2, %0" : "+v"(t3) : "v"(u3), "v"(pp.w));
            }
            float ex = __expf((t0 + t1) + (t2 + t3));
            int eid = (q < 3) ? (lane + 64 * q) : (192 + lane);
            alp[eid] = ex;
            atomicAdd(&dsF[d], ex);
        }

        // aggregate: hb[n] = (sum ex*xl[s]) / dsum[n] + cbias  (+LR if c%3<2)
        {
            const int half = lane >> 5, c4 = (lane & 31) * 4;
            const bool doact = (c % 3) < 2;
            float4 cb4 = *reinterpret_cast<const float4*>(&cbias[c * H + c4]);
            #pragma unroll 2
            for (int np = 0; np < 12; ++np) {
                int n = np * 2 + half;
                int q1 = eoff[n + 1];
                float s0 = 0.f, s1 = 0.f, s2 = 0.f, s3 = 0.f;
                for (int q = eoff[n]; q < q1; ++q) {
                    unsigned e = elist[q];
                    float al = alp[e & 255];
                    uint2 wv = *reinterpret_cast<const uint2*>(&xlb[(e >> 8) * HSS + c4]);
                    s0 = fmaf(h2f((unsigned short)wv.x), al, s0);
                    s1 = fmaf(h2f((unsigned short)(wv.x >> 16)), al, s1);
                    s2 = fmaf(h2f((unsigned short)wv.y), al, s2);
                    s3 = fmaf(h2f((unsigned short)(wv.y >> 16)), al, s3);
                }
                float inv = __builtin_amdgcn_rcpf(dsF[n]);
                float o0 = fmaf(s0, inv, cb4.x);
                float o1 = fmaf(s1, inv, cb4.y);
                float o2 = fmaf(s2, inv, cb4.z);
                float o3 = fmaf(s3, inv, cb4.w);
                if (doact) {
                    o0 = lrelu(o0, 0.01f); o1 = lrelu(o1, 0.01f);
                    o2 = lrelu(o2, 0.01f); o3 = lrelu(o3, 0.01f);
                }
                uint2 pk;
                pk.x = (unsigned)f2h(o0) | ((unsigned)f2h(o1) << 16);
                pk.y = (unsigned)f2h(o2) | ((unsigned)f2h(o3) << 16);
                *reinterpret_cast<uint2*>(&hb[n * HSS + c4]) = pk;
            }
        }
    }

    // ---------- pool + head MLP (alp region reused as scratch) ----------
    float* z = alp;                        // f32[136]
    {
        float p0 = 0.f, p1 = 0.f;
        #pragma unroll
        for (int r = 0; r < P; ++r) {
            unsigned wv = *reinterpret_cast<const unsigned*>(&hb[r * HSS + lane * 2]);
            p0 += h2f((unsigned short)wv);
            p1 += h2f((unsigned short)(wv >> 16));
        }
        z[lane * 2] = p0; z[lane * 2 + 1] = p1;
        if (lane < 8) z[128 + lane] = extra[(long long)g * 8 + lane];
    }
    float* h1 = (float*)(L + O_ALP + 576); // f32[128] (over dead dsum/elist)
    {
        int j0 = lane * 2;
        float a0 = bf0[j0], a1 = bf0[j0 + 1];
        for (int k = 0; k < H + 8; ++k) {
            float zk = z[k];
            float2 wv = *reinterpret_cast<const float2*>(&Wf0[k * H + j0]);
            a0 = fmaf(zk, wv.x, a0); a1 = fmaf(zk, wv.y, a1);
        }
        h1[j0] = lrelu(a0, 0.01f); h1[j0 + 1] = lrelu(a1, 0.01f);
    }
    float* hv2 = z;                        // reuse (z dead after L0)
    {
        int j0 = lane * 2;
        float a0 = bf1[j0], a1 = bf1[j0 + 1];
        for (int k = 0; k < H; ++k) {
            float hk = h1[k];
            float2 wv = *reinterpret_cast<const float2*>(&Wf1[k * H + j0]);
            a0 = fmaf(hk, wv.x, a0); a1 = fmaf(hk, wv.y, a1);
        }
        hv2[j0] = lrelu(a0, 0.01f); hv2[j0 + 1] = lrelu(a1, 0.01f);
    }
    {
        float p0 = 0.f, p1 = 0.f, p2 = 0.f;
        #pragma unroll
        for (int kk = 0; kk < 2; ++kk) {
            int k = lane * 2 + kk;
            float hk = hv2[k];
            p0 = fmaf(hk, Wf2[k * NOUT + 0], p0);
            p1 = fmaf(hk, Wf2[k * NOUT + 1], p1);
            p2 = fmaf(hk, Wf2[k * NOUT + 2], p2);
        }
        #pragma unroll
        for (int d = 1; d < 64; d <<= 1) {
            p0 += __shfl_xor(p0, d);
            p1 += __shfl_xor(p1, d);
            p2 += __shfl_xor(p2, d);
        }
        if (lane == 0) {
            out[(long long)g * NOUT + 0] = p0 + bf2[0];
            out[(long long)g * NOUT + 1] = p1 + bf2[1];
            out[(long long)g * NOUT + 2] = p2 + bf2[2];
        }
    }
}

extern "C" void kernel_launch(void* const* d_in, const int* in_sizes, int n_in,
                              void* d_out, int out_size, void* d_ws, size_t ws_size,
                              hipStream_t stream) {
    (void)in_sizes; (void)n_in; (void)out_size; (void)ws_size;
    const float* x     = (const float*)d_in[0];
    const int*   src   = (const int*)  d_in[1];
    const int*   dst   = (const int*)  d_in[2];
    const float* extra = (const float*)d_in[4];
    const float* W0    = (const float*)d_in[5];
    const float* b0    = (const float*)d_in[6];
    const float* W1    = (const float*)d_in[7];
    const float* b1    = (const float*)d_in[8];
    const float* Wl    = (const float*)d_in[9];
    const float* bl    = (const float*)d_in[10];
    const float* Wr    = (const float*)d_in[11];
    const float* br    = (const float*)d_in[12];
    const float* att   = (const float*)d_in[13];
    const float* cbias = (const float*)d_in[14];
    const float* Wf0   = (const float*)d_in[15];
    const float* bf0   = (const float*)d_in[16];
    const float* Wf1   = (const float*)d_in[17];
    const float* bf1   = (const float*)d_in[18];
    const float* Wf2   = (const float*)d_in[19];
    const float* bf2   = (const float*)d_in[20];
    unsigned short* wsb = (unsigned short*)d_ws;
    float* out = (float*)d_out;

    cvtw<<<848, 256, 0, stream>>>(W0, W1, Wl, Wr, att, bl, br, wsb);
    gat_all<<<NG, 64, 0, stream>>>(x, src, dst, extra, b0, b1, bl, br, att, cbias,
                                   Wf0, bf0, Wf1, bf1, Wf2, bf2, wsb, out);
}